// Round 1
// 219.174 us; speedup vs baseline: 1.0972x; 1.0972x over previous
//
#include <hip/hip_runtime.h>
#include <hip/hip_bf16.h>

typedef unsigned short u16;
typedef unsigned int u32;
using bf16x8 = __attribute__((ext_vector_type(8))) short;  // 8 bf16 (4 VGPRs)
using f32x4  = __attribute__((ext_vector_type(4))) float;  // 4 fp32

#define BB 512
#define TT 256
#define CC 192
#define HH 64

__device__ __forceinline__ u16 f2bf(float f) {
    __hip_bfloat16 h = __float2bfloat16(f);   // RNE
    u16 u; __builtin_memcpy(&u, &h, 2); return u;
}

// ================= prep kernels =================

// W_sw: B-fragment-swizzled weights. Frag fid = n3*6+ks (n3 = mat*4 + ntile, ks = K-step).
// lane (quad,l15) element u  =  W[c = ks*32+quad*8+u][h = (n3&3)*16+l15] of matrix n3>>2.
__global__ void wprep_kernel(const float* __restrict__ Wq,
                             const float* __restrict__ Wk,
                             const float* __restrict__ Wv,
                             u16* __restrict__ W_sw) {
    int gid  = blockIdx.x * 256 + threadIdx.x;   // 0..4607 (72 frags * 64 lanes)
    int fid  = gid >> 6, lane = gid & 63;
    int n3   = fid / 6,  ks   = fid % 6;
    int l15  = lane & 15, quad = lane >> 4;
    const float* W = (n3 < 4) ? Wq : (n3 < 8) ? Wk : Wv;
    const int h = (n3 & 3) * 16 + l15;
    u16* dst = W_sw + (size_t)gid * 8;
    #pragma unroll
    for (int u = 0; u < 8; ++u) {
        int c = ks * 32 + quad * 8 + u;
        dst[u] = f2bf(W[c * HH + h]);
    }
}

// poskT[h][t], posqT[h][t]
__global__ void pos_kernel(const float* __restrict__ Wk,
                           const float* __restrict__ Wq,
                           const float* __restrict__ pe,
                           float* __restrict__ poskT, float* __restrict__ posqT) {
    int t = blockIdx.x * 4 + (threadIdx.x >> 6);   // grid 64 x 256
    int h = threadIdx.x & 63;
    float ak = 0.f, aq = 0.f;
    for (int c = 0; c < CC; ++c) {
        float p = pe[t * CC + c];             // group-uniform broadcast
        ak += p * Wk[c * HH + h];             // coalesced
        aq += p * Wq[c * HH + h];
    }
    poskT[h * TT + t] = ak;
    posqT[h * TT + t] = aq;
}

// bias in C/D-fragment layout: bias_sw[(i*16+jt)*64 + lane] = float4 over r,
// component r = bias[row t0+quad*4+r][col jt*16+l15]  (only jt<=i written/read)
__global__ void bias_kernel(const float* __restrict__ poskT,
                            const float* __restrict__ posqT,
                            float4* __restrict__ bias_sw) {
    const int i = blockIdx.x >> 4, jt = blockIdx.x & 15;
    if (jt > i) return;
    const int lane = threadIdx.x;
    const int l15 = lane & 15, quad = lane >> 4;
    const int tq = i * 16 + quad * 4;     // query rows tq..tq+3
    const int jc = jt * 16 + l15;         // key col
    float s[4] = {0.f, 0.f, 0.f, 0.f};
    for (int h = 0; h < HH; ++h) {
        float pq = posqT[h * TT + jc];
        #pragma unroll
        for (int r = 0; r < 4; ++r)
            s[r] += poskT[h * TT + tq + r] * pq;
    }
    bias_sw[blockIdx.x * 64 + lane] = make_float4(s[0], s[1], s[2], s[3]);
}

// ================= kernel 1: QKV projection GEMM (W in registers) =================
// grid 2048: block = (b = blk>>2, rb = blk&3) covers rows rb*64..+63 of batch b.
// Wave w owns h-tile w of ALL THREE matrices (Q,K,V) x all 4 m-tiles.
//  -> W fragments needed per wave: 3 mats x 6 ks = 18 bf16x8 = 72 VGPRs, hoisted
//     into registers BEFORE staging so their L2 latency hides under X loads.
//  -> inner loop is pure ds_read_b128 + MFMA (no global loads, no vmcnt stalls).
#define XP 200   // LDS X pitch (elems); mult of 8 for 16B-aligned ds_read_b128

__global__ __launch_bounds__(256, 3)
void qkv_kernel(const float* __restrict__ x,
                const u16* __restrict__ W_sw,
                u16* __restrict__ q_sw, u16* __restrict__ k_sw,
                u16* __restrict__ vg) {
    __shared__ __align__(16) u16 xs[64 * XP];   // 25,600 B
    const int tid  = threadIdx.x;
    const int w    = tid >> 6;
    const int lane = tid & 63;
    const int l15  = lane & 15;
    const int quad = lane >> 4;
    const int b    = blockIdx.x >> 2;
    const int rb   = blockIdx.x & 3;
    const float* xb = x + ((size_t)b * TT + rb * 64) * CC;   // 64 contiguous rows

    // ---- hoist W fragments for this wave's h-tile (issue FIRST: latency
    //      overlaps the X staging below; all L2-resident after block 0) ----
    const bf16x8* Wv8 = (const bf16x8*)W_sw;
    bf16x8 Wf[18];                              // [mat][ks], mat: 0=Q 1=K 2=V
    #pragma unroll
    for (int mat = 0; mat < 3; ++mat)
        #pragma unroll
        for (int ks = 0; ks < 6; ++ks)
            Wf[mat * 6 + ks] = Wv8[(((mat * 4 + w) * 6) + ks) * 64 + lane];

    // ---- stage X -> LDS bf16 (coalesced: adjacent tids read adjacent float4) ----
    #pragma unroll
    for (int it = 0; it < 12; ++it) {
        const int flat = (it * 256 + tid) * 4;       // 0..12287
        const int row = flat / CC, col = flat % CC;
        const float4 v = *(const float4*)(xb + flat);
        uint2 pk;
        pk.x = (u32)f2bf(v.x) | ((u32)f2bf(v.y) << 16);
        pk.y = (u32)f2bf(v.z) | ((u32)f2bf(v.w) << 16);
        *(uint2*)&xs[row * XP + col] = pk;
    }
    __syncthreads();

    // ---- MFMA: wave w computes h-tile w of Q,K,V for all 4 m-tiles ----
    f32x4 acc[12];                              // [m][mat] = acc[m*3+mat]
    #pragma unroll
    for (int i = 0; i < 12; ++i) acc[i] = {0.f, 0.f, 0.f, 0.f};
    #pragma unroll
    for (int ks = 0; ks < 6; ++ks) {
        bf16x8 a[4];
        #pragma unroll
        for (int m = 0; m < 4; ++m)
            a[m] = *(const bf16x8*)&xs[(m * 16 + l15) * XP + ks * 32 + quad * 8];
        #pragma unroll
        for (int m = 0; m < 4; ++m)
            #pragma unroll
            for (int mat = 0; mat < 3; ++mat)
                acc[m * 3 + mat] = __builtin_amdgcn_mfma_f32_16x16x32_bf16(
                    a[m], Wf[mat * 6 + ks], acc[m * 3 + mat], 0, 0, 0);
    }

    // ---- epilogue: h-tile index is w ----
    const int hs    = w >> 1;
    const int quadp = (w * 2 + (l15 >> 3)) & 3;
    const int u     = l15 & 7;
    #pragma unroll
    for (int m = 0; m < 4; ++m) {
        const int i_loc  = rb * 4 + m;                 // t-tile within batch (0..15)
        const size_t bi  = (size_t)b * 16 + i_loc;
        const size_t base = (bi * 2 + hs) * 512 + (quadp * 16 + quad * 4) * 8 + u;
        #pragma unroll
        for (int r = 0; r < 4; ++r) {
            q_sw[base + r * 8] = f2bf(acc[m * 3 + 0][r]);   // Q -> A-frag layout
            k_sw[base + r * 8] = f2bf(acc[m * 3 + 1][r]);   // K -> B-frag layout
        }
        const size_t t_glob = (size_t)b * TT + i_loc * 16;
        #pragma unroll
        for (int r = 0; r < 4; ++r)
            vg[(t_glob + quad * 4 + r) * HH + w * 16 + l15] = f2bf(acc[m * 3 + 2][r]);
    }
}

// ================= kernel 2: lean flash attention =================
// LDS: Vt[64][264] + per-wave P[16][40] = 38,912 B -> 4 blocks/CU.
// grid 1024 (2 blocks/batch); wave tile sets balanced to SumJ = 17 each.
#define VP 264
#define PP 40
#define VT_ELEMS (HH * VP)               // 16896
#define P_ELEMS 640                      // 16*40
#define LDSB_ELEMS (VT_ELEMS + 4 * P_ELEMS)

__global__ __launch_bounds__(256, 4)
void attn_kernel(const u16* __restrict__ q_sw, const u16* __restrict__ k_sw,
                 const u16* __restrict__ vg, const float4* __restrict__ bias_sw,
                 float* __restrict__ out) {
    __shared__ __align__(16) u16 lds[LDSB_ELEMS];
    const int tid  = threadIdx.x;
    const int w    = tid >> 6;
    const int lane = tid & 63;
    const int l15  = lane & 15;
    const int quad = lane >> 4;
    const int b    = blockIdx.x >> 1;
    const int half = blockIdx.x & 1;

    // ---- stage V^T: thread tid handles key-row j = tid ----
    {
        const u16* vrow = vg + ((size_t)b * TT + tid) * HH;
        #pragma unroll
        for (int u2 = 0; u2 < 8; ++u2) {
            bf16x8 vv = *(const bf16x8*)(vrow + u2 * 8);
            #pragma unroll
            for (int e = 0; e < 8; ++e)
                lds[(u2 * 8 + e) * VP + tid] = (u16)vv[e];
        }
    }
    __syncthreads();

    u16* Pw = &lds[VT_ELEMS + w * P_ELEMS];
    const float scale = 0.07216878364870322f;  // 192^-0.5
    const f32x4 zero4 = {0.f, 0.f, 0.f, 0.f};
    const bf16x8* qv = (const bf16x8*)q_sw;
    const bf16x8* kv = (const bf16x8*)k_sw;

    #pragma unroll 1
    for (int mt = 0; mt < 2; ++mt) {
        // balanced causal tile sets: half0 w: {w, 15-w}; half1 w: {4+w, 11-w}
        const int i  = half ? (mt ? 11 - w : 4 + w) : (mt ? 15 - w : w);
        const int t0 = 16 * i;
        const int J  = i + 1;
        const int Pq = (J + 1) >> 1;
        const size_t bi = (size_t)b * 16 + i;

        const bf16x8 qf0 = qv[(bi * 2 + 0) * 64 + lane];   // coalesced 1KB
        const bf16x8 qf1 = qv[(bi * 2 + 1) * 64 + lane];

        f32x4 o[4];
        float m4[4], l4[4];
        #pragma unroll
        for (int n = 0; n < 4; ++n) o[n] = zero4;
        #pragma unroll
        for (int r = 0; r < 4; ++r) { m4[r] = -1e30f; l4[r] = 0.f; }

        #pragma unroll
        for (int p = 0; p < 8; ++p) {
            if (p < Pq) {
                const int jt0 = 2 * p, jt1 = 2 * p + 1;
                // ---- S tiles (pair), all loads coalesced ----
                f32x4 sa = zero4, sb;
                {
                    const size_t bj = (size_t)b * 16 + jt0;
                    bf16x8 k0 = kv[(bj * 2 + 0) * 64 + lane];
                    bf16x8 k1 = kv[(bj * 2 + 1) * 64 + lane];
                    sa = __builtin_amdgcn_mfma_f32_16x16x32_bf16(qf0, k0, sa, 0, 0, 0);
                    sa = __builtin_amdgcn_mfma_f32_16x16x32_bf16(qf1, k1, sa, 0, 0, 0);
                    const float4 b4 = bias_sw[(i * 16 + jt0) * 64 + lane];
                    sa[0] = sa[0] * scale + b4.x;
                    sa[1] = sa[1] * scale + b4.y;
                    sa[2] = sa[2] * scale + b4.z;
                    sa[3] = sa[3] * scale + b4.w;
                    if (jt0 == i) {
                        #pragma unroll
                        for (int r = 0; r < 4; ++r)
                            if (l15 > quad * 4 + r) sa[r] = -1e30f;
                    }
                }
                if (jt1 < J) {
                    sb = zero4;
                    const size_t bj = (size_t)b * 16 + jt1;
                    bf16x8 k0 = kv[(bj * 2 + 0) * 64 + lane];
                    bf16x8 k1 = kv[(bj * 2 + 1) * 64 + lane];
                    sb = __builtin_amdgcn_mfma_f32_16x16x32_bf16(qf0, k0, sb, 0, 0, 0);
                    sb = __builtin_amdgcn_mfma_f32_16x16x32_bf16(qf1, k1, sb, 0, 0, 0);
                    const float4 b4 = bias_sw[(i * 16 + jt1) * 64 + lane];
                    sb[0] = sb[0] * scale + b4.x;
                    sb[1] = sb[1] * scale + b4.y;
                    sb[2] = sb[2] * scale + b4.z;
                    sb[3] = sb[3] * scale + b4.w;
                    if (jt1 == i) {
                        #pragma unroll
                        for (int r = 0; r < 4; ++r)
                            if (l15 > quad * 4 + r) sb[r] = -1e30f;
                    }
                } else {
                    sb[0] = -1e30f; sb[1] = -1e30f; sb[2] = -1e30f; sb[3] = -1e30f;
                }
                // ---- pair row max (16-lane group shares rows) ----
                float t4[4];
                #pragma unroll
                for (int r = 0; r < 4; ++r) t4[r] = fmaxf(sa[r], sb[r]);
                #pragma unroll
                for (int d = 1; d < 16; d <<= 1) {
                    #pragma unroll
                    for (int r = 0; r < 4; ++r) t4[r] = fmaxf(t4[r], __shfl_xor(t4[r], d, 64));
                }
                // ---- online rescale ----
                float al[4];
                #pragma unroll
                for (int r = 0; r < 4; ++r) {
                    float mn = fmaxf(m4[r], t4[r]);
                    al[r] = __expf(m4[r] - mn);   // first pair: exp(-huge)=0
                    m4[r] = mn;
                    l4[r] *= al[r];
                }
                #pragma unroll
                for (int n = 0; n < 4; ++n)
                #pragma unroll
                for (int r = 0; r < 4; ++r) o[n][r] *= al[r];
                // ---- exp + P -> per-wave LDS ----
                #pragma unroll
                for (int r = 0; r < 4; ++r) {
                    float e0 = __expf(sa[r] - m4[r]);
                    float e1 = __expf(sb[r] - m4[r]);   // invalid tile -> exp(-huge)=0
                    l4[r] += e0 + e1;                   // per-lane partial, reduced later
                    Pw[(quad * 4 + r) * PP + l15]      = f2bf(e0);
                    Pw[(quad * 4 + r) * PP + 16 + l15] = f2bf(e1);
                }
                // ---- PV ----
                bf16x8 pa = *(const bf16x8*)&Pw[l15 * PP + quad * 8];
                #pragma unroll
                for (int n = 0; n < 4; ++n) {
                    bf16x8 bv = *(const bf16x8*)&lds[(n * 16 + l15) * VP + p * 32 + quad * 8];
                    o[n] = __builtin_amdgcn_mfma_f32_16x16x32_bf16(pa, bv, o[n], 0, 0, 0);
                }
            }
        }
        // ---- row-sum reduce + normalize + store ----
        #pragma unroll
        for (int d = 1; d < 16; d <<= 1) {
            #pragma unroll
            for (int r = 0; r < 4; ++r) l4[r] += __shfl_xor(l4[r], d, 64);
        }
        float rl4[4];
        #pragma unroll
        for (int r = 0; r < 4; ++r) rl4[r] = 1.f / l4[r];
        float* ob = out + ((size_t)b * TT + t0) * HH;
        #pragma unroll
        for (int n = 0; n < 4; ++n)
        #pragma unroll
        for (int r = 0; r < 4; ++r)
            ob[(quad * 4 + r) * HH + n * 16 + l15] = o[n][r] * rl4[r];
    }
}

extern "C" void kernel_launch(void* const* d_in, const int* in_sizes, int n_in,
                              void* d_out, int out_size, void* d_ws, size_t ws_size,
                              hipStream_t stream) {
    const float* x  = (const float*)d_in[0];
    const float* Wk = (const float*)d_in[1];
    const float* Wq = (const float*)d_in[2];
    const float* Wv = (const float*)d_in[3];
    const float* pe = (const float*)d_in[4];
    float* out = (float*)d_out;

    // ws: poskT[16384]f | posqT[16384]f | bias_sw[16384]float4-elems(f) | W_sw[36864]u16
    //     | q_sw | k_sw | vg   (bf16, 16 MB each)  == 50,798,592 B total (same as r5)
    float*  poskT  = (float*)d_ws;
    float*  posqT  = poskT + TT * HH;
    float4* biassw = (float4*)(posqT + TT * HH);
    u16*    W_sw   = (u16*)((float*)biassw + TT * TT);
    u16*    q_sw   = W_sw + 3 * HH * CC;
    u16*    k_sw   = q_sw + (size_t)BB * TT * HH;
    u16*    vg     = k_sw + (size_t)BB * TT * HH;

    wprep_kernel<<<18, 256, 0, stream>>>(Wq, Wk, Wv, W_sw);
    pos_kernel<<<TT / 4, 256, 0, stream>>>(Wk, Wq, pe, poskT, posqT);
    bias_kernel<<<256, 64, 0, stream>>>(poskT, posqT, biassw);
    qkv_kernel<<<4 * BB, 256, 0, stream>>>(x, W_sw, q_sw, k_sw, vg);
    attn_kernel<<<2 * BB, 256, 0, stream>>>(q_sw, k_sw, vg, biassw, out);
}